// Round 4
// baseline (6466.576 us; speedup 1.0000x reference)
//
#include <hip/hip_runtime.h>
#include <hip/hip_bf16.h>

#define H 1024
#define B3H 3072
#define BATCH 128
#define TSTEPS 256

typedef __attribute__((ext_vector_type(8))) short short8;
typedef __attribute__((ext_vector_type(4))) float f32x4;

static __device__ __forceinline__ float bf2f(__hip_bfloat16 v) { return __bfloat162float(v); }
static __device__ __forceinline__ unsigned short f2bf_bits(float f) {
    __hip_bfloat16 h = __float2bfloat16(f);
    return __builtin_bit_cast(unsigned short, h);
}
static __device__ __forceinline__ float bits2f(unsigned short b) {
    return bf2f(__builtin_bit_cast(__hip_bfloat16, b));
}
static __device__ __forceinline__ unsigned short bfbits(__hip_bfloat16 v) {
    return __builtin_bit_cast(unsigned short, v);
}
// Split fp32 into bf16 hi + bf16 lo residual (hi + lo ≈ v to ~17 mantissa bits)
static __device__ __forceinline__ void split_bf(float v, unsigned short& hi, unsigned short& lo) {
    hi = f2bf_bits(v);
    lo = f2bf_bits(v - bits2f(hi));
}

// ws layout:
//   [0]        int flag: 1 = inputs stored as bf16, 0 = fp32 (R2/R3: fp32)
//   pw_hi      12,582,912 B  bf16(W) MFMA B-fragments
//   pw_lo      12,582,912 B  bf16(W - bf16(W)) residual fragments
//   hbuf0/1, xbuf: fp32 state carries, 512 KiB each
#define PW_OFF   256
#define PWL_OFF  (PW_OFF + 12582912)
#define HB0_OFF  (PWL_OFF + 12582912)
#define HB1_OFF  (HB0_OFF + 524288)
#define XB_OFF   (HB1_OFF + 524288)

__global__ void detect_dtype(const unsigned int* __restrict__ w, int* __restrict__ flag) {
    __shared__ int cnt[256];
    int c = 0;
    for (int i = threadIdx.x; i < 4096; i += 256) {
        unsigned int v = (w[i] >> 8) & 0x7f;
        c += (v >= 0x33 && v <= 0x3f) ? 1 : 0;
    }
    cnt[threadIdx.x] = c;
    __syncthreads();
    for (int s = 128; s > 0; s >>= 1) {
        if (threadIdx.x < s) cnt[threadIdx.x] += cnt[threadIdx.x + s];
        __syncthreads();
    }
    if (threadIdx.x == 0) *flag = (cnt[0] * 2 > 4096) ? 1 : 0;
}

// ---------------------------------------------------------------------------
// Pack K and R [1024 x 3072] row-major into MFMA B-fragment layout, as a
// bf16 hi/lo pair (lo = residual of fp32 weight after bf16 rounding).
// lane holds B[k = kc*32 + (lane>>4)*8 + j][n = it*32 + ns*16 + (lane&15)].
// ---------------------------------------------------------------------------
__global__ void pack_w(const void* __restrict__ Kp, const void* __restrict__ Rp,
                       __hip_bfloat16* __restrict__ pwh, __hip_bfloat16* __restrict__ pwl,
                       const int* __restrict__ flag) {
    int idx = blockIdx.x * 256 + threadIdx.x;
    int lane = idx & 63;
    int kc   = (idx >> 6) & 31;
    int ns   = (idx >> 11) & 1;
    int it   = (idx >> 12) & 31;
    int g    = idx >> 17;
    if (g >= 6) return;
    const int isbf = *flag;
    int col   = (g % 3) * 1024 + it * 32 + ns * 16 + (lane & 15);
    int kbase = kc * 32 + (lane >> 4) * 8;
    unsigned short eh[8], el[8];
    if (isbf) {
        const __hip_bfloat16* src = (const __hip_bfloat16*)((g < 3) ? Kp : Rp);
#pragma unroll
        for (int j = 0; j < 8; ++j) { eh[j] = bfbits(src[(size_t)(kbase + j) * B3H + col]); el[j] = 0; }
    } else {
        const float* src = (const float*)((g < 3) ? Kp : Rp);
#pragma unroll
        for (int j = 0; j < 8; ++j) split_bf(src[(size_t)(kbase + j) * B3H + col], eh[j], el[j]);
    }
    uint4 vh, vl;
    vh.x = (unsigned int)eh[0] | ((unsigned int)eh[1] << 16);
    vh.y = (unsigned int)eh[2] | ((unsigned int)eh[3] << 16);
    vh.z = (unsigned int)eh[4] | ((unsigned int)eh[5] << 16);
    vh.w = (unsigned int)eh[6] | ((unsigned int)eh[7] << 16);
    vl.x = (unsigned int)el[0] | ((unsigned int)el[1] << 16);
    vl.y = (unsigned int)el[2] | ((unsigned int)el[3] << 16);
    vl.z = (unsigned int)el[4] | ((unsigned int)el[5] << 16);
    vl.w = (unsigned int)el[6] | ((unsigned int)el[7] << 16);
    *(uint4*)(pwh + (size_t)idx * 8) = vh;
    *(uint4*)(pwl + (size_t)idx * 8) = vl;
}

__global__ void init_bufs(const void* __restrict__ cin, const void* __restrict__ hs,
                          float* __restrict__ xbuf, float* __restrict__ hbuf,
                          const int* __restrict__ flag) {
    int i = blockIdx.x * 256 + threadIdx.x;
    if (i >= BATCH * H) return;
    if (*flag) {
        xbuf[i] = bf2f(((const __hip_bfloat16*)cin)[i]);
        hbuf[i] = bf2f(((const __hip_bfloat16*)hs)[i]);
    } else {
        xbuf[i] = ((const float*)cin)[i];
        hbuf[i] = ((const float*)hs)[i];
    }
}

// ---------------------------------------------------------------------------
// One GRU step. Grid: 128 WGs (4 batch-tiles x 32 i-tiles), 384 threads
// (6 waves: 0=xz 1=xr 2=xh 3=hz 4=hr 5=hh). A and W both carried as bf16
// hi/lo pairs; GEMM = AhWh + AhWl + AlWh (~fp32-accurate; error no longer
// compounds through the 256-step feedback loop).
// ---------------------------------------------------------------------------
__launch_bounds__(384)
__global__ void gru_step(const float* __restrict__ xsrc,
                         const float* __restrict__ hsrc,
                         float* __restrict__ hdst,
                         const __hip_bfloat16* __restrict__ pwh,
                         const __hip_bfloat16* __restrict__ pwl,
                         const void* __restrict__ bias,
                         void* __restrict__ out,
                         const int* __restrict__ flag,
                         int t, int same_xh, int write_hf) {
    __shared__ unsigned short sA[4 * 32 * 264];  // 67584 B

    const int tid  = threadIdx.x;
    const int wave = tid >> 6;
    const int lane = tid & 63;
    const int bt = blockIdx.x >> 5;
    const int it = blockIdx.x & 31;
    const int bbase = bt * 32;
    const int m0 = lane & 15;
    const int q  = lane >> 4;

    const int g = wave;
    const size_t boff0 = ((size_t)((g * 32 + it) * 2 + 0) * 32) * 64 + lane;
    const size_t boff1 = ((size_t)((g * 32 + it) * 2 + 1) * 32) * 64 + lane;
    const uint4* bh0 = (const uint4*)pwh + boff0;
    const uint4* bh1 = (const uint4*)pwh + boff1;
    const uint4* bl0 = (const uint4*)pwl + boff0;
    const uint4* bl1 = (const uint4*)pwl + boff1;

    const int tile_hi = (g < 3) ? 0 : (same_xh ? 0 : 2);
    const unsigned short* aHi = sA + tile_hi * (32 * 264);
    const unsigned short* aLo = aHi + (32 * 264);

    f32x4 acc00 = {0.f, 0.f, 0.f, 0.f};
    f32x4 acc01 = {0.f, 0.f, 0.f, 0.f};
    f32x4 acc10 = {0.f, 0.f, 0.f, 0.f};
    f32x4 acc11 = {0.f, 0.f, 0.f, 0.f};

    const int nsrc = same_xh ? 1 : 2;
    for (int kb = 0; kb < 4; ++kb) {
        __syncthreads();
        for (int idx4 = tid; idx4 < 2048 * nsrc; idx4 += 384) {
            int srct = idx4 >> 11;
            int rem  = idx4 & 2047;
            int row  = rem >> 6;
            int kg   = rem & 63;
            const float* src = (srct == 0) ? xsrc : hsrc;
            const float4 v = *(const float4*)&src[(size_t)(bbase + row) * H + kb * 256 + kg * 4];
            unsigned short h0, h1, h2, h3, l0, l1, l2, l3;
            split_bf(v.x, h0, l0);
            split_bf(v.y, h1, l1);
            split_bf(v.z, h2, l2);
            split_bf(v.w, h3, l3);
            uint2 ph, pl;
            ph.x = (unsigned int)h0 | ((unsigned int)h1 << 16);
            ph.y = (unsigned int)h2 | ((unsigned int)h3 << 16);
            pl.x = (unsigned int)l0 | ((unsigned int)l1 << 16);
            pl.y = (unsigned int)l2 | ((unsigned int)l3 << 16);
            *(uint2*)&sA[(srct * 2 + 0) * (32 * 264) + row * 264 + kg * 4] = ph;
            *(uint2*)&sA[(srct * 2 + 1) * (32 * 264) + row * 264 + kg * 4] = pl;
        }
        __syncthreads();
#pragma unroll
        for (int kc = 0; kc < 8; ++kc) {
            const int kcg = kb * 8 + kc;
            short8 b0h = __builtin_bit_cast(short8, bh0[(size_t)kcg * 64]);
            short8 b1h = __builtin_bit_cast(short8, bh1[(size_t)kcg * 64]);
            short8 b0l = __builtin_bit_cast(short8, bl0[(size_t)kcg * 64]);
            short8 b1l = __builtin_bit_cast(short8, bl1[(size_t)kcg * 64]);
            const int koff = kc * 32 + q * 8;
            short8 a0h = *(const short8*)&aHi[m0 * 264 + koff];
            short8 a1h = *(const short8*)&aHi[(m0 + 16) * 264 + koff];
            short8 a0l = *(const short8*)&aLo[m0 * 264 + koff];
            short8 a1l = *(const short8*)&aLo[(m0 + 16) * 264 + koff];
            // Ah @ Wh
            acc00 = __builtin_amdgcn_mfma_f32_16x16x32_bf16(a0h, b0h, acc00, 0, 0, 0);
            acc01 = __builtin_amdgcn_mfma_f32_16x16x32_bf16(a0h, b1h, acc01, 0, 0, 0);
            acc10 = __builtin_amdgcn_mfma_f32_16x16x32_bf16(a1h, b0h, acc10, 0, 0, 0);
            acc11 = __builtin_amdgcn_mfma_f32_16x16x32_bf16(a1h, b1h, acc11, 0, 0, 0);
            // Ah @ Wl
            acc00 = __builtin_amdgcn_mfma_f32_16x16x32_bf16(a0h, b0l, acc00, 0, 0, 0);
            acc01 = __builtin_amdgcn_mfma_f32_16x16x32_bf16(a0h, b1l, acc01, 0, 0, 0);
            acc10 = __builtin_amdgcn_mfma_f32_16x16x32_bf16(a1h, b0l, acc10, 0, 0, 0);
            acc11 = __builtin_amdgcn_mfma_f32_16x16x32_bf16(a1h, b1l, acc11, 0, 0, 0);
            // Al @ Wh
            acc00 = __builtin_amdgcn_mfma_f32_16x16x32_bf16(a0l, b0h, acc00, 0, 0, 0);
            acc01 = __builtin_amdgcn_mfma_f32_16x16x32_bf16(a0l, b1h, acc01, 0, 0, 0);
            acc10 = __builtin_amdgcn_mfma_f32_16x16x32_bf16(a1l, b0h, acc10, 0, 0, 0);
            acc11 = __builtin_amdgcn_mfma_f32_16x16x32_bf16(a1l, b1h, acc11, 0, 0, 0);
        }
    }

    __syncthreads();
    float* sG = (float*)sA;
    {
        // C/D layout: col = lane&15, row = (lane>>4)*4 + reg  [m89/m91 verified]
#pragma unroll
        for (int r = 0; r < 4; ++r) {
            int mrow = q * 4 + r;
            sG[g * 1024 + mrow * 32 + m0]             = acc00[r];
            sG[g * 1024 + mrow * 32 + m0 + 16]        = acc01[r];
            sG[g * 1024 + (mrow + 16) * 32 + m0]      = acc10[r];
            sG[g * 1024 + (mrow + 16) * 32 + m0 + 16] = acc11[r];
        }
    }
    __syncthreads();

    const int isbf = *flag;
    const __hip_bfloat16* bias_b = (const __hip_bfloat16*)bias;
    const float* bias_f = (const float*)bias;
    __hip_bfloat16* outb = (__hip_bfloat16*)out;
    float* outf = (float*)out;

    const int ibase0 = it * 32;
    for (int e = tid; e < 1024; e += 384) {
        int mloc = e >> 5;
        int nloc = e & 31;
        int b = bbase + mloc;
        int i = ibase0 + nloc;
        float xz = sG[0 * 1024 + e], xr = sG[1 * 1024 + e], xh = sG[2 * 1024 + e];
        float hz = sG[3 * 1024 + e], hr = sG[4 * 1024 + e], hh = sG[5 * 1024 + e];
        float bi0 = isbf ? bf2f(bias_b[i])              : bias_f[i];
        float bi1 = isbf ? bf2f(bias_b[1024 + i])       : bias_f[1024 + i];
        float bi2 = isbf ? bf2f(bias_b[2048 + i])       : bias_f[2048 + i];
        float br0 = isbf ? bf2f(bias_b[B3H + i])        : bias_f[B3H + i];
        float br1 = isbf ? bf2f(bias_b[B3H + 1024 + i]) : bias_f[B3H + 1024 + i];
        float br2 = isbf ? bf2f(bias_b[B3H + 2048 + i]) : bias_f[B3H + 2048 + i];
        float zlin = xz + bi0 + hz + br0;
        float rlin = xr + bi1 + hr + br1;
        float xht  = xh + bi2;
        float hht  = hh + br2;   // recurrent bias INSIDE r*(...) (reset_after)
        float z  = 1.0f / (1.0f + expf(-zlin));
        float r  = 1.0f / (1.0f + expf(-rlin));
        float hc = tanhf(xht + r * hht);
        float hold = hsrc[(size_t)b * H + i];
        float hnew = z * hold + (1.0f - z) * hc;
        hdst[(size_t)b * H + i] = hnew;
        size_t o1 = (size_t)b * (TSTEPS * H) + (size_t)t * H + i;
        size_t o2 = (size_t)BATCH * TSTEPS * H + (size_t)b * H + i;
        if (isbf) {
            outb[o1] = __float2bfloat16(hnew);
            if (write_hf) outb[o2] = __float2bfloat16(hnew);
        } else {
            outf[o1] = hnew;
            if (write_hf) outf[o2] = hnew;
        }
    }
}

extern "C" void kernel_launch(void* const* d_in, const int* in_sizes, int n_in,
                              void* d_out, int out_size, void* d_ws, size_t ws_size,
                              hipStream_t stream) {
    const void* cin  = d_in[0];
    const void* hs   = d_in[1];
    const void* Kw   = d_in[2];
    const void* Rw   = d_in[3];
    const void* bias = d_in[4];

    char* ws = (char*)d_ws;
    int* flag = (int*)ws;
    __hip_bfloat16* pwh = (__hip_bfloat16*)(ws + PW_OFF);
    __hip_bfloat16* pwl = (__hip_bfloat16*)(ws + PWL_OFF);
    float* hbuf0 = (float*)(ws + HB0_OFF);
    float* hbuf1 = (float*)(ws + HB1_OFF);
    float* xbuf  = (float*)(ws + XB_OFF);

    detect_dtype<<<1, 256, 0, stream>>>((const unsigned int*)Kw, flag);
    pack_w<<<3072, 256, 0, stream>>>(Kw, Rw, pwh, pwl, flag);
    init_bufs<<<512, 256, 0, stream>>>(cin, hs, xbuf, hbuf0, flag);

    float* hb[2] = {hbuf0, hbuf1};
    for (int t = 0; t < TSTEPS; ++t) {
        const float* hsrc = hb[t & 1];
        float* hdst = hb[(t + 1) & 1];
        const float* xsrc = (t == 0) ? (const float*)xbuf : hsrc;
        gru_step<<<128, 384, 0, stream>>>(xsrc, hsrc, hdst, pwh, pwl, bias, (void*)d_out, flag,
                                          t, (t == 0) ? 0 : 1, (t == TSTEPS - 1) ? 1 : 0);
    }
}

// Round 5
// 4569.214 us; speedup vs baseline: 1.4152x; 1.4152x over previous
//
#include <hip/hip_runtime.h>
#include <hip/hip_bf16.h>

#define H 1024
#define B3H 3072
#define BATCH 128
#define TSTEPS 256
#define LROW 520                 // 512 k-chunk + 8 pad (shorts)
#define PLANE (16 * LROW)        // one 16-row bf16 plane per chunk

typedef __attribute__((ext_vector_type(8))) short short8;
typedef __attribute__((ext_vector_type(4))) float f32x4;

static __device__ __forceinline__ float bf2f(__hip_bfloat16 v) { return __bfloat162float(v); }
static __device__ __forceinline__ unsigned short f2bf_bits(float f) {
    __hip_bfloat16 h = __float2bfloat16(f);
    return __builtin_bit_cast(unsigned short, h);
}
static __device__ __forceinline__ float bits2f(unsigned short b) {
    return bf2f(__builtin_bit_cast(__hip_bfloat16, b));
}
static __device__ __forceinline__ unsigned short bfbits(__hip_bfloat16 v) {
    return __builtin_bit_cast(unsigned short, v);
}
static __device__ __forceinline__ void split_bf(float v, unsigned short& hi, unsigned short& lo) {
    hi = f2bf_bits(v);
    lo = f2bf_bits(v - bits2f(hi));
}

// ws layout
#define PW_OFF   256
#define PWL_OFF  (PW_OFF + 12582912)
#define XHI_OFF  (PWL_OFF + 12582912)
#define XLO_OFF  (XHI_OFF + 262144)
#define H0HI_OFF (XLO_OFF + 262144)
#define H0LO_OFF (H0HI_OFF + 262144)
#define H1HI_OFF (H0LO_OFF + 262144)
#define H1LO_OFF (H1HI_OFF + 262144)

__global__ void detect_dtype(const unsigned int* __restrict__ w, int* __restrict__ flag) {
    __shared__ int cnt[256];
    int c = 0;
    for (int i = threadIdx.x; i < 4096; i += 256) {
        unsigned int v = (w[i] >> 8) & 0x7f;
        c += (v >= 0x33 && v <= 0x3f) ? 1 : 0;
    }
    cnt[threadIdx.x] = c;
    __syncthreads();
    for (int s = 128; s > 0; s >>= 1) {
        if (threadIdx.x < s) cnt[threadIdx.x] += cnt[threadIdx.x + s];
        __syncthreads();
    }
    if (threadIdx.x == 0) *flag = (cnt[0] * 2 > 4096) ? 1 : 0;
}

// Pack W into MFMA B-fragment layout, bf16 hi/lo pair (unchanged from R4 — verified).
__global__ void pack_w(const void* __restrict__ Kp, const void* __restrict__ Rp,
                       __hip_bfloat16* __restrict__ pwh, __hip_bfloat16* __restrict__ pwl,
                       const int* __restrict__ flag) {
    int idx = blockIdx.x * 256 + threadIdx.x;
    int lane = idx & 63;
    int kc   = (idx >> 6) & 31;
    int ns   = (idx >> 11) & 1;
    int it   = (idx >> 12) & 31;
    int g    = idx >> 17;
    if (g >= 6) return;
    const int isbf = *flag;
    int col   = (g % 3) * 1024 + it * 32 + ns * 16 + (lane & 15);
    int kbase = kc * 32 + (lane >> 4) * 8;
    unsigned short eh[8], el[8];
    if (isbf) {
        const __hip_bfloat16* src = (const __hip_bfloat16*)((g < 3) ? Kp : Rp);
#pragma unroll
        for (int j = 0; j < 8; ++j) { eh[j] = bfbits(src[(size_t)(kbase + j) * B3H + col]); el[j] = 0; }
    } else {
        const float* src = (const float*)((g < 3) ? Kp : Rp);
#pragma unroll
        for (int j = 0; j < 8; ++j) split_bf(src[(size_t)(kbase + j) * B3H + col], eh[j], el[j]);
    }
    uint4 vh, vl;
    vh.x = (unsigned int)eh[0] | ((unsigned int)eh[1] << 16);
    vh.y = (unsigned int)eh[2] | ((unsigned int)eh[3] << 16);
    vh.z = (unsigned int)eh[4] | ((unsigned int)eh[5] << 16);
    vh.w = (unsigned int)eh[6] | ((unsigned int)eh[7] << 16);
    vl.x = (unsigned int)el[0] | ((unsigned int)el[1] << 16);
    vl.y = (unsigned int)el[2] | ((unsigned int)el[3] << 16);
    vl.z = (unsigned int)el[4] | ((unsigned int)el[5] << 16);
    vl.w = (unsigned int)el[6] | ((unsigned int)el[7] << 16);
    *(uint4*)(pwh + (size_t)idx * 8) = vh;
    *(uint4*)(pwl + (size_t)idx * 8) = vl;
}

// Inputs -> pre-split bf16 hi/lo planes.
__global__ void init_bufs(const void* __restrict__ cin, const void* __restrict__ hs,
                          unsigned short* __restrict__ xhi, unsigned short* __restrict__ xlo,
                          unsigned short* __restrict__ hhi, unsigned short* __restrict__ hlo,
                          const int* __restrict__ flag) {
    int i = blockIdx.x * 256 + threadIdx.x;
    if (i >= BATCH * H) return;
    float xv, hv;
    if (*flag) {
        xv = bf2f(((const __hip_bfloat16*)cin)[i]);
        hv = bf2f(((const __hip_bfloat16*)hs)[i]);
    } else {
        xv = ((const float*)cin)[i];
        hv = ((const float*)hs)[i];
    }
    unsigned short a, b;
    split_bf(xv, a, b); xhi[i] = a; xlo[i] = b;
    split_bf(hv, a, b); hhi[i] = a; hlo[i] = b;
}

// ---------------------------------------------------------------------------
// One GRU step. Grid 256 WGs = 8 batch-tiles(16 rows) x 32 col-slices(32 cols),
// 384 threads = 6 gate-waves. Wave g computes [16 x 32] of gate g.
// A (= h, pre-split bf16 hi/lo) staged via pure copy; W hi/lo streamed from L2.
// GEMM = AhWh + AhWl + AlWh per 16x16x32 MFMA triple.
// ---------------------------------------------------------------------------
__launch_bounds__(384)
__global__ void gru_step(const unsigned short* __restrict__ aAhi,  // gates 0-2 source (x at t=0, else h)
                         const unsigned short* __restrict__ aAlo,
                         const unsigned short* __restrict__ aBhi,  // gates 3-5 source (= h, also "hold")
                         const unsigned short* __restrict__ aBlo,
                         unsigned short* __restrict__ dsthi,
                         unsigned short* __restrict__ dstlo,
                         const __hip_bfloat16* __restrict__ pwh,
                         const __hip_bfloat16* __restrict__ pwl,
                         const void* __restrict__ bias,
                         void* __restrict__ out,
                         const int* __restrict__ flag,
                         int t, int same_xh, int write_hf) {
    // planes: [0]=A_hi [1]=A_lo [2]=B_hi [3]=B_lo (2/3 only when !same_xh)
    __shared__ unsigned short sA[4 * PLANE];  // 66560 B

    const int tid  = threadIdx.x;
    const int g    = tid >> 6;        // gate wave 0..5
    const int lane = tid & 63;
    const int bt = blockIdx.x >> 5;   // 0..7, 16-row tiles
    const int it = blockIdx.x & 31;   // 0..31, 32-col slices (XCD = it%8)
    const int bbase = bt * 16;
    const int m0 = lane & 15;
    const int q  = lane >> 4;

    const size_t boff0 = ((size_t)((g * 32 + it) * 2 + 0) * 32) * 64 + lane;
    const size_t boff1 = ((size_t)((g * 32 + it) * 2 + 1) * 32) * 64 + lane;
    const uint4* bh0 = (const uint4*)pwh + boff0;
    const uint4* bh1 = (const uint4*)pwh + boff1;
    const uint4* bl0 = (const uint4*)pwl + boff0;
    const uint4* bl1 = (const uint4*)pwl + boff1;

    const unsigned short* aH = sA + (((g < 3) || same_xh) ? 0 : 2) * PLANE;
    const unsigned short* aL = aH + PLANE;

    f32x4 acc0 = {0.f, 0.f, 0.f, 0.f};
    f32x4 acc1 = {0.f, 0.f, 0.f, 0.f};

    const int nplanes = same_xh ? 2 : 4;
    const int nGr = nplanes * 1024;   // 16 rows x 64 granules per plane

    for (int c = 0; c < 2; ++c) {     // two 512-k chunks
        if (c) __syncthreads();
        const int kstart = c * 512;
        for (int g4 = tid; g4 < nGr; g4 += 384) {
            int plane = g4 >> 10;
            int rem   = g4 & 1023;
            int row   = rem >> 6;
            int kg    = rem & 63;
            const unsigned short* src =
                (plane == 0) ? aAhi : (plane == 1) ? aAlo : (plane == 2) ? aBhi : aBlo;
            uint4 v = *(const uint4*)&src[(size_t)(bbase + row) * H + kstart + kg * 8];
            *(uint4*)&sA[plane * PLANE + row * LROW + kg * 8] = v;
        }
        __syncthreads();
#pragma unroll 4
        for (int kc = 0; kc < 16; ++kc) {
            const int kcg = c * 16 + kc;
            short8 b0h = __builtin_bit_cast(short8, bh0[(size_t)kcg * 64]);
            short8 b1h = __builtin_bit_cast(short8, bh1[(size_t)kcg * 64]);
            short8 b0l = __builtin_bit_cast(short8, bl0[(size_t)kcg * 64]);
            short8 b1l = __builtin_bit_cast(short8, bl1[(size_t)kcg * 64]);
            const int koff = kc * 32 + q * 8;
            short8 a_h = *(const short8*)&aH[m0 * LROW + koff];
            short8 a_l = *(const short8*)&aL[m0 * LROW + koff];
            acc0 = __builtin_amdgcn_mfma_f32_16x16x32_bf16(a_h, b0h, acc0, 0, 0, 0);
            acc1 = __builtin_amdgcn_mfma_f32_16x16x32_bf16(a_h, b1h, acc1, 0, 0, 0);
            acc0 = __builtin_amdgcn_mfma_f32_16x16x32_bf16(a_h, b0l, acc0, 0, 0, 0);
            acc1 = __builtin_amdgcn_mfma_f32_16x16x32_bf16(a_h, b1l, acc1, 0, 0, 0);
            acc0 = __builtin_amdgcn_mfma_f32_16x16x32_bf16(a_l, b0h, acc0, 0, 0, 0);
            acc1 = __builtin_amdgcn_mfma_f32_16x16x32_bf16(a_l, b1h, acc1, 0, 0, 0);
        }
    }

    __syncthreads();
    // 6 gate planes [16 x 32] fp32 in LDS (12 KB, aliases sA)
    float* sG = (float*)sA;
    {
        // C/D layout: col = lane&15, row = (lane>>4)*4 + reg  [m89/m91 verified]
#pragma unroll
        for (int r = 0; r < 4; ++r) {
            int mrow = q * 4 + r;
            sG[g * 512 + mrow * 32 + m0]      = acc0[r];
            sG[g * 512 + mrow * 32 + m0 + 16] = acc1[r];
        }
    }
    __syncthreads();

    const int isbf = *flag;
    const __hip_bfloat16* bias_b = (const __hip_bfloat16*)bias;
    const float* bias_f = (const float*)bias;
    __hip_bfloat16* outb = (__hip_bfloat16*)out;
    float* outf = (float*)out;

    const int ibase0 = it * 32;
    for (int e = tid; e < 512; e += 384) {
        int mloc = e >> 5;
        int nloc = e & 31;
        int b = bbase + mloc;
        int i = ibase0 + nloc;
        float xz = sG[0 * 512 + e], xr = sG[1 * 512 + e], xh = sG[2 * 512 + e];
        float hz = sG[3 * 512 + e], hr = sG[4 * 512 + e], hh = sG[5 * 512 + e];
        float bi0 = isbf ? bf2f(bias_b[i])              : bias_f[i];
        float bi1 = isbf ? bf2f(bias_b[1024 + i])       : bias_f[1024 + i];
        float bi2 = isbf ? bf2f(bias_b[2048 + i])       : bias_f[2048 + i];
        float br0 = isbf ? bf2f(bias_b[B3H + i])        : bias_f[B3H + i];
        float br1 = isbf ? bf2f(bias_b[B3H + 1024 + i]) : bias_f[B3H + 1024 + i];
        float br2 = isbf ? bf2f(bias_b[B3H + 2048 + i]) : bias_f[B3H + 2048 + i];
        float zlin = xz + bi0 + hz + br0;
        float rlin = xr + bi1 + hr + br1;
        float xht  = xh + bi2;
        float hht  = hh + br2;   // recurrent bias INSIDE r*(...) (reset_after)
        float z  = 1.0f / (1.0f + expf(-zlin));
        float r  = 1.0f / (1.0f + expf(-rlin));
        float hc = tanhf(xht + r * hht);
        size_t hidx = (size_t)b * H + i;
        float hold = bits2f(aBhi[hidx]) + bits2f(aBlo[hidx]);
        float hnew = z * hold + (1.0f - z) * hc;
        unsigned short nh, nl;
        split_bf(hnew, nh, nl);
        dsthi[hidx] = nh;
        dstlo[hidx] = nl;
        size_t o1 = (size_t)b * (TSTEPS * H) + (size_t)t * H + i;
        size_t o2 = (size_t)BATCH * TSTEPS * H + hidx;
        if (isbf) {
            outb[o1] = __float2bfloat16(hnew);
            if (write_hf) outb[o2] = __float2bfloat16(hnew);
        } else {
            outf[o1] = hnew;
            if (write_hf) outf[o2] = hnew;
        }
    }
}

extern "C" void kernel_launch(void* const* d_in, const int* in_sizes, int n_in,
                              void* d_out, int out_size, void* d_ws, size_t ws_size,
                              hipStream_t stream) {
    const void* cin  = d_in[0];
    const void* hs   = d_in[1];
    const void* Kw   = d_in[2];
    const void* Rw   = d_in[3];
    const void* bias = d_in[4];

    char* ws = (char*)d_ws;
    int* flag = (int*)ws;
    __hip_bfloat16* pwh = (__hip_bfloat16*)(ws + PW_OFF);
    __hip_bfloat16* pwl = (__hip_bfloat16*)(ws + PWL_OFF);
    unsigned short* xhi  = (unsigned short*)(ws + XHI_OFF);
    unsigned short* xlo  = (unsigned short*)(ws + XLO_OFF);
    unsigned short* hhi[2] = {(unsigned short*)(ws + H0HI_OFF), (unsigned short*)(ws + H1HI_OFF)};
    unsigned short* hlo[2] = {(unsigned short*)(ws + H0LO_OFF), (unsigned short*)(ws + H1LO_OFF)};

    detect_dtype<<<1, 256, 0, stream>>>((const unsigned int*)Kw, flag);
    pack_w<<<3072, 256, 0, stream>>>(Kw, Rw, pwh, pwl, flag);
    init_bufs<<<512, 256, 0, stream>>>(cin, hs, xhi, xlo, hhi[0], hlo[0], flag);

    for (int t = 0; t < TSTEPS; ++t) {
        int cur = t & 1, nxt = (t + 1) & 1;
        const unsigned short* Ahi = (t == 0) ? xhi : hhi[cur];
        const unsigned short* Alo = (t == 0) ? xlo : hlo[cur];
        gru_step<<<256, 384, 0, stream>>>(Ahi, Alo, hhi[cur], hlo[cur],
                                          hhi[nxt], hlo[nxt], pwh, pwl, bias,
                                          (void*)d_out, flag,
                                          t, (t == 0) ? 0 : 1, (t == TSTEPS - 1) ? 1 : 0);
    }
}